// Round 2
// baseline (314.522 us; speedup 1.0000x reference)
//
#include <hip/hip_runtime.h>
#include <math.h>

// Round 7: break the 1-block/CU barrier serialization. Fused kernel retiled to
// 64 T-rows x 4 waves, LDS 71,680 B -> 2 blocks/CU (independent blocks overlap
// each other's barrier/vmcnt drains). GBK=32 for weight GEMM phases. x chunk
// register-prefetch in phase 1. prep_kv folded into kv-GEMM epilogue (packed
// per-(b,h) K/Vt written directly; padding pre-zeroed by hipMemsetAsync).

#define NUM_HEADS 8
#define DIM_HEAD 40
#define INNER 320
#define DQ 320
#define DC 768
#define SEQ_T 4096
#define SEQ_S 77
#define BATCH 16
#define M_TOTAL (BATCH * SEQ_T)  // 65536
#define MKV 1232                  // BATCH*SEQ_S
#define MKV_PAD 1280
#define SCALE 0.39763536438352531f

typedef __attribute__((ext_vector_type(8))) short short8;
typedef __attribute__((ext_vector_type(4))) float floatx4;

__device__ __forceinline__ unsigned short f2bf(float f) {
  unsigned u = __float_as_uint(f);
  u += 0x7FFFu + ((u >> 16) & 1u);   // RNE
  return (unsigned short)(u >> 16);
}

// ------------------------------------------------------- convert ctx to bf16
#define CTXBLKS (MKV_PAD * DC / 8 / 256)        // 480
__global__ __launch_bounds__(256) void convert_ctx_kernel(
    const float* __restrict__ ctx, unsigned short* __restrict__ ctxb) {
  size_t t = (size_t)blockIdx.x * 256 + threadIdx.x;  // 8-short unit
  int row = (int)(t / (DC / 8)), col = (int)(t % (DC / 8)) * 8;
  int4 pk = make_int4(0, 0, 0, 0);
  if (row < MKV) {
    const float* p = &ctx[(size_t)row * DC + col];
    float4 a = *(const float4*)p, b = *(const float4*)(p + 4);
    pk.x = (int)(f2bf(a.x) | ((unsigned)f2bf(a.y) << 16));
    pk.y = (int)(f2bf(a.z) | ((unsigned)f2bf(a.w) << 16));
    pk.z = (int)(f2bf(b.x) | ((unsigned)f2bf(b.y) << 16));
    pk.w = (int)(f2bf(b.z) | ((unsigned)f2bf(b.w) << 16));
  }
  *(int4*)&ctxb[(size_t)row * DC + col] = pk;
}

// -------------------------------------- transpose weights (fp32 -> bf16^T)
__global__ __launch_bounds__(256) void transpose_w_kernel(
    const float* __restrict__ Wq, const float* __restrict__ Wo,
    const float* __restrict__ Wk, const float* __restrict__ Wv,
    unsigned short* __restrict__ WqT, unsigned short* __restrict__ WoT,
    unsigned short* __restrict__ WkvT) {
  const int z = blockIdx.z;
  const float* W; unsigned short* WT; int KD; float scl = 1.0f;
  if (z == 0)      { W = Wq; WT = WqT;  KD = 320; }
  else if (z == 1) { W = Wo; WT = WoT;  KD = 320; }
  else if (z == 2) { W = Wk; WT = WkvT; KD = DC; scl = SCALE; }
  else             { W = Wv; WT = WkvT + (size_t)INNER * DC; KD = DC; }
  const int k0 = blockIdx.x * 32;
  if (k0 >= KD) return;
  const int n0 = blockIdx.y * 32;
  __shared__ float tile[32][33];
  int tx = threadIdx.x & 31, ty = threadIdx.x >> 5;
  #pragma unroll
  for (int r = 0; r < 4; ++r)
    tile[ty + r * 8][tx] = W[(size_t)(k0 + ty + r * 8) * 320 + n0 + tx];
  __syncthreads();
  #pragma unroll
  for (int r = 0; r < 4; ++r)
    WT[(size_t)(n0 + ty + r * 8) * KD + k0 + tx] = f2bf(tile[tx][ty + r * 8] * scl);
}

// ---------------- kv GEMM with fused pack epilogue -------------------------
// C = ctxb[1280x768] @ WkvT^T -> packed kvp[(b*8+h)]: K[80][40] | Vt[48][104]
// (kvp pre-zeroed by hipMemsetAsync so padding rows/cols stay 0).
#define GBM 128
#define GBN 160
#define GBK 64

__global__ __launch_bounds__(256) void gemm_kv_pack_kernel(
    const unsigned short* __restrict__ A, const unsigned short* __restrict__ B,
    unsigned short* __restrict__ kvp) {
  __shared__ __align__(16) unsigned short As[GBM * GBK];
  __shared__ __align__(16) unsigned short Bs[GBN * GBK];
  const int tid = threadIdx.x;
  const int lane = tid & 63, wave = tid >> 6;
  const int wm = (wave & 1) * 64, wn = (wave >> 1) * 80;
  const int lrow = lane & 15, quad = lane >> 4;
  const unsigned short* Ab = A + (size_t)blockIdx.x * GBM * DC;
  const unsigned short* Bb = B + (size_t)blockIdx.y * GBN * DC;

  floatx4 acc[4][5];
  #pragma unroll
  for (int i = 0; i < 4; ++i)
    #pragma unroll
    for (int j = 0; j < 5; ++j) acc[i][j] = (floatx4){0.f, 0.f, 0.f, 0.f};

  for (int kb = 0; kb < DC / GBK; ++kb) {
    const int k0 = kb * GBK;
    #pragma unroll
    for (int rnd = 0; rnd < 4; ++rnd) {
      int off = rnd * 4096 + tid * 16;
      int m = off >> 7, cl = (off >> 4) & 7, cg = cl ^ (m & 7);
      __builtin_amdgcn_global_load_lds(
          (const __attribute__((address_space(1))) void*)(Ab + (size_t)m * DC + k0 + cg * 8),
          (__attribute__((address_space(3))) void*)((char*)As + off), 16, 0, 0);
    }
    #pragma unroll
    for (int rnd = 0; rnd < 5; ++rnd) {
      int off = rnd * 4096 + tid * 16;
      int n = off >> 7, cl = (off >> 4) & 7, cg = cl ^ (n & 7);
      __builtin_amdgcn_global_load_lds(
          (const __attribute__((address_space(1))) void*)(Bb + (size_t)n * DC + k0 + cg * 8),
          (__attribute__((address_space(3))) void*)((char*)Bs + off), 16, 0, 0);
    }
    __syncthreads();
    #pragma unroll
    for (int ks = 0; ks < 2; ++ks) {
      short8 fa[4], fb[5];
      #pragma unroll
      for (int i = 0; i < 4; ++i) {
        int m = wm + i * 16 + lrow;
        int cl = (ks * 4 + quad) ^ (m & 7);
        fa[i] = *(const short8*)&As[m * GBK + cl * 8];
      }
      #pragma unroll
      for (int j = 0; j < 5; ++j) {
        int n = wn + j * 16 + lrow;
        int cl = (ks * 4 + quad) ^ (n & 7);
        fb[j] = *(const short8*)&Bs[n * GBK + cl * 8];
      }
      #pragma unroll
      for (int i = 0; i < 4; ++i)
        #pragma unroll
        for (int j = 0; j < 5; ++j)
          acc[i][j] = __builtin_amdgcn_mfma_f32_16x16x32_bf16(fa[i], fb[j], acc[i][j], 0, 0, 0);
    }
    __syncthreads();
  }
  // pack epilogue: n<320 -> K[s][c] (pre-scaled by SCALE via WkvT), else Vt[c][s]
  #pragma unroll
  for (int i = 0; i < 4; ++i)
    #pragma unroll
    for (int j = 0; j < 5; ++j) {
      int n = blockIdx.y * GBN + wn + j * 16 + lrow;
      #pragma unroll
      for (int r = 0; r < 4; ++r) {
        int m = blockIdx.x * GBM + wm + i * 16 + quad * 4 + r;
        if (m < MKV) {
          unsigned um = (unsigned)m;
          int b = (int)(um / 77u), s = (int)(um - (unsigned)b * 77u);
          unsigned short* base = kvp + (size_t)b * (NUM_HEADS * 8192);
          unsigned short v = f2bf(acc[i][j][r]);
          if (n < 320) {
            unsigned un = (unsigned)n;
            int h = (int)(un / 40u), c = (int)(un - (unsigned)h * 40u);
            base[(size_t)h * 8192 + s * 40 + c] = v;
          } else {
            unsigned un = (unsigned)(n - 320);
            int h = (int)(un / 40u), c = (int)(un - (unsigned)h * 40u);
            base[(size_t)h * 8192 + 3200 + c * 104 + s] = v;
          }
        }
      }
    }
}

// --------------------------------------------------------------- fused kernel
// grid = B * T/64 = 1024 blocks, 256 threads (4 waves). LDS 71,680 B ->
// 2 blocks/CU. Layout (shorts): qs [64][328] @ 0; stage @ 20992:
// phase1 As[64*32] | Bs[320*32]; phase2 Kb[80*40] | Vt[48*104] | Pw 4x[16*104];
// phase3 Bs[320*32].
#define QS_STRIDE 328
#define S0 20992

__global__ __launch_bounds__(256) void fused_attn_kernel(
    const float* __restrict__ x, const unsigned short* __restrict__ WqT,
    const unsigned short* __restrict__ kvp, const unsigned short* __restrict__ WoT,
    const float* __restrict__ bo, float* __restrict__ out) {
  __shared__ __align__(16) unsigned short lds[35840];   // 71,680 B
  unsigned short* qs = lds;                 // [64][328]
  const int tid = threadIdx.x;
  const int lane = tid & 63, wave = tid >> 6;
  const int lrow = lane & 15, quad = lane >> 4;
  const int b = blockIdx.x >> 6;
  const int t0 = (blockIdx.x & 63) * 64;
  const int wn = wave * 80;

  // ---- Phase 1: qs = bf16(SCALE * x[t0:t0+64] @ Wq), K-step 32 ----
  {
    unsigned short* As = lds + S0;          // [64][32]
    unsigned short* Bs = lds + S0 + 2048;   // [320][32]
    const float* xb = x + ((size_t)b * SEQ_T + t0) * DQ;
    floatx4 acc[4][5];
    #pragma unroll
    for (int i = 0; i < 4; ++i)
      #pragma unroll
      for (int j = 0; j < 5; ++j) acc[i][j] = (floatx4){0.f, 0.f, 0.f, 0.f};

    const int soff = tid * 16;              // byte offset in As (4096 B)
    const int sm = soff >> 6;               // row
    const int scl = (soff >> 4) & 3;
    const int scg = scl ^ (sm & 3);
    const float* xsrc = xb + (size_t)sm * DQ + scg * 8;
    float4 xa = *(const float4*)xsrc, xc = *(const float4*)(xsrc + 4);

    for (int kb = 0; kb < 10; ++kb) {
      float4 na, nc;
      if (kb < 9) {                         // prefetch next x chunk
        const float* s = xsrc + (size_t)(kb + 1) * 32;
        na = *(const float4*)s; nc = *(const float4*)(s + 4);
      }
      short8 pk;
      pk[0] = (short)f2bf(xa.x); pk[1] = (short)f2bf(xa.y);
      pk[2] = (short)f2bf(xa.z); pk[3] = (short)f2bf(xa.w);
      pk[4] = (short)f2bf(xc.x); pk[5] = (short)f2bf(xc.y);
      pk[6] = (short)f2bf(xc.z); pk[7] = (short)f2bf(xc.w);
      *(short8*)((char*)As + soff) = pk;
      #pragma unroll
      for (int rnd = 0; rnd < 5; ++rnd) {   // Bs: WqT chunk (20,480 B)
        int off = rnd * 4096 + tid * 16;
        int n = off >> 6, cl = (off >> 4) & 3, cg = cl ^ (n & 3);
        __builtin_amdgcn_global_load_lds(
            (const __attribute__((address_space(1))) void*)(WqT + (size_t)n * 320 + kb * 32 + cg * 8),
            (__attribute__((address_space(3))) void*)((char*)Bs + off), 16, 0, 0);
      }
      __syncthreads();
      short8 fa[4], fb[5];
      #pragma unroll
      for (int i = 0; i < 4; ++i) {
        int m = i * 16 + lrow;
        fa[i] = *(const short8*)&As[m * 32 + ((quad ^ (m & 3)) * 8)];
      }
      #pragma unroll
      for (int j = 0; j < 5; ++j) {
        int n = wn + j * 16 + lrow;
        fb[j] = *(const short8*)&Bs[n * 32 + ((quad ^ (n & 3)) * 8)];
      }
      #pragma unroll
      for (int i = 0; i < 4; ++i)
        #pragma unroll
        for (int j = 0; j < 5; ++j)
          acc[i][j] = __builtin_amdgcn_mfma_f32_16x16x32_bf16(fa[i], fb[j], acc[i][j], 0, 0, 0);
      __syncthreads();
      if (kb < 9) { xa = na; xc = nc; }
    }
    #pragma unroll
    for (int i = 0; i < 4; ++i)
      #pragma unroll
      for (int j = 0; j < 5; ++j)
        #pragma unroll
        for (int r = 0; r < 4; ++r)
          qs[(i * 16 + quad * 4 + r) * QS_STRIDE + wn + j * 16 + lrow] =
              f2bf(acc[i][j][r] * SCALE);
  }
  __syncthreads();

  // ---- Phase 2: attention; att overwrites qs band [h*40, h*40+40) ----
  {
    unsigned short* Kb = lds + S0;                      // [80][40]
    unsigned short* Vt = lds + S0 + 3200;               // [48][104]
    unsigned short* Pw = lds + S0 + 8192 + wave * 1664; // [16][104]
    const short8 zero8 = {0, 0, 0, 0, 0, 0, 0, 0};
    for (int h = 0; h < NUM_HEADS; ++h) {
      const unsigned short* kvbh = kvp + (size_t)(b * NUM_HEADS + h) * 8192;
      #pragma unroll
      for (int rnd = 0; rnd < 4; ++rnd) {   // linear 16 KB: K then Vt
        int off = rnd * 4096 + tid * 16;
        __builtin_amdgcn_global_load_lds(
            (const __attribute__((address_space(1))) void*)((const char*)kvbh + off),
            (__attribute__((address_space(3))) void*)((char*)Kb + off), 16, 0, 0);
      }
      __syncthreads();
      const int qrow = wave * 16 + lrow;
      short8 fq0 = *(const short8*)&qs[qrow * QS_STRIDE + h * DIM_HEAD + quad * 8];
      short8 fq1 = (quad == 0)
                       ? *(const short8*)&qs[qrow * QS_STRIDE + h * DIM_HEAD + 32]
                       : zero8;
      floatx4 sc[5];
      #pragma unroll
      for (int j = 0; j < 5; ++j) sc[j] = (floatx4){0.f, 0.f, 0.f, 0.f};
      #pragma unroll
      for (int j = 0; j < 5; ++j) {
        int srow = j * 16 + lrow;
        short8 fb0 = *(const short8*)&Kb[srow * 40 + quad * 8];
        short8 fb1 = *(const short8*)&Kb[srow * 40 + 32 + quad * 8];  // x0 for quad!=0
        sc[j] = __builtin_amdgcn_mfma_f32_16x16x32_bf16(fq0, fb0, sc[j], 0, 0, 0);
        sc[j] = __builtin_amdgcn_mfma_f32_16x16x32_bf16(fq1, fb1, sc[j], 0, 0, 0);
      }
      float lsum[4] = {0.f, 0.f, 0.f, 0.f};
      #pragma unroll
      for (int j = 0; j < 5; ++j) {
        int s = j * 16 + lrow;
        #pragma unroll
        for (int r = 0; r < 4; ++r) {
          float p = (s < SEQ_S) ? __expf(sc[j][r]) : 0.f;
          Pw[(quad * 4 + r) * 104 + s] = f2bf(p);
          lsum[r] += p;
        }
      }
      #pragma unroll
      for (int r = 0; r < 4; ++r) Pw[(quad * 4 + r) * 104 + 80 + lrow] = 0;
      #pragma unroll
      for (int r = 0; r < 4; ++r) {
        float v = lsum[r];
        v += __shfl_xor(v, 1); v += __shfl_xor(v, 2);
        v += __shfl_xor(v, 4); v += __shfl_xor(v, 8);
        lsum[r] = 1.0f / v;
      }
      floatx4 oc[3];
      #pragma unroll
      for (int nj = 0; nj < 3; ++nj) oc[nj] = (floatx4){0.f, 0.f, 0.f, 0.f};
      #pragma unroll
      for (int ks = 0; ks < 3; ++ks) {   // Pw wave-local: lgkmcnt ordering ok
        short8 pa = *(const short8*)&Pw[lrow * 104 + ks * 32 + quad * 8];
        #pragma unroll
        for (int nj = 0; nj < 3; ++nj) {
          short8 vb = *(const short8*)&Vt[(nj * 16 + lrow) * 104 + ks * 32 + quad * 8];
          oc[nj] = __builtin_amdgcn_mfma_f32_16x16x32_bf16(pa, vb, oc[nj], 0, 0, 0);
        }
      }
      #pragma unroll
      for (int nj = 0; nj < 3; ++nj) {   // att -> qs (wave-local rows)
        int c = nj * 16 + lrow;
        if (c < DIM_HEAD) {
          #pragma unroll
          for (int r = 0; r < 4; ++r)
            qs[(wave * 16 + quad * 4 + r) * QS_STRIDE + h * DIM_HEAD + c] =
                f2bf(oc[nj][r] * lsum[r]);
        }
      }
      __syncthreads();   // all Kb/Vt reads done before next head's restage
    }
  }

  // ---- Phase 3: out = att @ Wo + bo (A straight from qs LDS), K-step 32 ----
  {
    unsigned short* Bs = lds + S0;          // [320][32]
    floatx4 acc[4][5];
    #pragma unroll
    for (int i = 0; i < 4; ++i)
      #pragma unroll
      for (int j = 0; j < 5; ++j) acc[i][j] = (floatx4){0.f, 0.f, 0.f, 0.f};
    for (int kb = 0; kb < 10; ++kb) {
      #pragma unroll
      for (int rnd = 0; rnd < 5; ++rnd) {
        int off = rnd * 4096 + tid * 16;
        int n = off >> 6, cl = (off >> 4) & 3, cg = cl ^ (n & 3);
        __builtin_amdgcn_global_load_lds(
            (const __attribute__((address_space(1))) void*)(WoT + (size_t)n * 320 + kb * 32 + cg * 8),
            (__attribute__((address_space(3))) void*)((char*)Bs + off), 16, 0, 0);
      }
      __syncthreads();
      short8 fa[4], fb[5];
      #pragma unroll
      for (int i = 0; i < 4; ++i)
        fa[i] = *(const short8*)&qs[(i * 16 + lrow) * QS_STRIDE + kb * 32 + quad * 8];
      #pragma unroll
      for (int j = 0; j < 5; ++j) {
        int n = wn + j * 16 + lrow;
        fb[j] = *(const short8*)&Bs[n * 32 + ((quad ^ (n & 3)) * 8)];
      }
      #pragma unroll
      for (int i = 0; i < 4; ++i)
        #pragma unroll
        for (int j = 0; j < 5; ++j)
          acc[i][j] = __builtin_amdgcn_mfma_f32_16x16x32_bf16(fa[i], fb[j], acc[i][j], 0, 0, 0);
      __syncthreads();
    }
    float* ob = out + ((size_t)b * SEQ_T + t0) * DQ;
    #pragma unroll
    for (int i = 0; i < 4; ++i)
      #pragma unroll
      for (int j = 0; j < 5; ++j) {
        int n = wn + j * 16 + lrow;
        float bv = bo[n];
        #pragma unroll
        for (int r = 0; r < 4; ++r)
          ob[(size_t)(i * 16 + quad * 4 + r) * DQ + n] = acc[i][j][r] + bv;
      }
  }
}

// -------------------------------------------------------------------- launch
extern "C" void kernel_launch(void* const* d_in, const int* in_sizes, int n_in,
                              void* d_out, int out_size, void* d_ws, size_t ws_size,
                              hipStream_t stream) {
  const float* x   = (const float*)d_in[0];
  const float* ctx = (const float*)d_in[1];
  const float* Wq  = (const float*)d_in[2];
  const float* Wk  = (const float*)d_in[3];
  const float* Wv  = (const float*)d_in[4];
  const float* Wo  = (const float*)d_in[5];
  const float* bo  = (const float*)d_in[6];
  float* out = (float*)d_out;

  char* w = (char*)d_ws;
  unsigned short* ctxb = (unsigned short*)(w);             //  1,966,080 B
  unsigned short* WkvT = (unsigned short*)(w + 1966080);   //    983,040 B
  unsigned short* WqT  = (unsigned short*)(w + 2949120);   //    204,800 B
  unsigned short* WoT  = (unsigned short*)(w + 3153920);   //    204,800 B
  unsigned short* kvp  = (unsigned short*)(w + 3358720);   //  2,097,152 B -> 5,455,872

  hipMemsetAsync(kvp, 0, 2097152, stream);   // zero-fill kvp padding
  hipLaunchKernelGGL(convert_ctx_kernel, dim3(CTXBLKS), dim3(256), 0, stream, ctx, ctxb);
  hipLaunchKernelGGL(transpose_w_kernel, dim3(24, 10, 4), dim3(256), 0, stream,
                     Wq, Wo, Wk, Wv, WqT, WoT, WkvT);
  hipLaunchKernelGGL(gemm_kv_pack_kernel, dim3(MKV_PAD / GBM, 640 / GBN),
                     dim3(256), 0, stream, ctxb, WkvT, kvp);
  hipLaunchKernelGGL(fused_attn_kernel, dim3(BATCH * (SEQ_T / 64)), dim3(256), 0, stream,
                     x, WqT, kvp, WoT, bo, out);
}

// Round 3
// 298.229 us; speedup vs baseline: 1.0546x; 1.0546x over previous
//
#include <hip/hip_runtime.h>
#include <math.h>

// Round 8: fused kernel LDS cut to 65,280 B (<= 64 KB) to restore 2 blocks/CU
// (round-7 evidence: >64KB LDS allocates a full CU -> 1 block -> every barrier
// stalls the whole CU). Phase1 As/Bs overlay the not-yet-written qs region and
// return to the conflict-free GBK=64 XOR8 swizzle; phase2 overlays Pw on Kb
// (extra barrier between QK and exp); phase3 uses a 128B-row pair-packed XOR8
// layout for Bs (round-7's 64B-row XOR4 was ~8-way bank conflicted).

#define NUM_HEADS 8
#define DIM_HEAD 40
#define INNER 320
#define DQ 320
#define DC 768
#define SEQ_T 4096
#define SEQ_S 77
#define BATCH 16
#define M_TOTAL (BATCH * SEQ_T)  // 65536
#define MKV 1232                  // BATCH*SEQ_S
#define MKV_PAD 1280
#define SCALE 0.39763536438352531f

typedef __attribute__((ext_vector_type(8))) short short8;
typedef __attribute__((ext_vector_type(4))) float floatx4;

__device__ __forceinline__ unsigned short f2bf(float f) {
  unsigned u = __float_as_uint(f);
  u += 0x7FFFu + ((u >> 16) & 1u);   // RNE
  return (unsigned short)(u >> 16);
}

// ------------------------------------------------------- convert ctx to bf16
#define CTXBLKS (MKV_PAD * DC / 8 / 256)        // 480
__global__ __launch_bounds__(256) void convert_ctx_kernel(
    const float* __restrict__ ctx, unsigned short* __restrict__ ctxb) {
  size_t t = (size_t)blockIdx.x * 256 + threadIdx.x;  // 8-short unit
  int row = (int)(t / (DC / 8)), col = (int)(t % (DC / 8)) * 8;
  int4 pk = make_int4(0, 0, 0, 0);
  if (row < MKV) {
    const float* p = &ctx[(size_t)row * DC + col];
    float4 a = *(const float4*)p, b = *(const float4*)(p + 4);
    pk.x = (int)(f2bf(a.x) | ((unsigned)f2bf(a.y) << 16));
    pk.y = (int)(f2bf(a.z) | ((unsigned)f2bf(a.w) << 16));
    pk.z = (int)(f2bf(b.x) | ((unsigned)f2bf(b.y) << 16));
    pk.w = (int)(f2bf(b.z) | ((unsigned)f2bf(b.w) << 16));
  }
  *(int4*)&ctxb[(size_t)row * DC + col] = pk;
}

// -------------------------------------- transpose weights (fp32 -> bf16^T)
__global__ __launch_bounds__(256) void transpose_w_kernel(
    const float* __restrict__ Wq, const float* __restrict__ Wo,
    const float* __restrict__ Wk, const float* __restrict__ Wv,
    unsigned short* __restrict__ WqT, unsigned short* __restrict__ WoT,
    unsigned short* __restrict__ WkvT) {
  const int z = blockIdx.z;
  const float* W; unsigned short* WT; int KD; float scl = 1.0f;
  if (z == 0)      { W = Wq; WT = WqT;  KD = 320; }
  else if (z == 1) { W = Wo; WT = WoT;  KD = 320; }
  else if (z == 2) { W = Wk; WT = WkvT; KD = DC; scl = SCALE; }
  else             { W = Wv; WT = WkvT + (size_t)INNER * DC; KD = DC; }
  const int k0 = blockIdx.x * 32;
  if (k0 >= KD) return;
  const int n0 = blockIdx.y * 32;
  __shared__ float tile[32][33];
  int tx = threadIdx.x & 31, ty = threadIdx.x >> 5;
  #pragma unroll
  for (int r = 0; r < 4; ++r)
    tile[ty + r * 8][tx] = W[(size_t)(k0 + ty + r * 8) * 320 + n0 + tx];
  __syncthreads();
  #pragma unroll
  for (int r = 0; r < 4; ++r)
    WT[(size_t)(n0 + ty + r * 8) * KD + k0 + tx] = f2bf(tile[tx][ty + r * 8] * scl);
}

// ---------------- kv GEMM with fused pack epilogue -------------------------
// C = ctxb[1280x768] @ WkvT^T -> packed kvp[(b*8+h)]: K[80][40] | Vt[48][104]
// (kvp pre-zeroed by hipMemsetAsync so padding stays 0, never NaN).
#define GBM 128
#define GBN 160
#define GBK 64

__global__ __launch_bounds__(256) void gemm_kv_pack_kernel(
    const unsigned short* __restrict__ A, const unsigned short* __restrict__ B,
    unsigned short* __restrict__ kvp) {
  __shared__ __align__(16) unsigned short As[GBM * GBK];
  __shared__ __align__(16) unsigned short Bs[GBN * GBK];
  const int tid = threadIdx.x;
  const int lane = tid & 63, wave = tid >> 6;
  const int wm = (wave & 1) * 64, wn = (wave >> 1) * 80;
  const int lrow = lane & 15, quad = lane >> 4;
  const unsigned short* Ab = A + (size_t)blockIdx.x * GBM * DC;
  const unsigned short* Bb = B + (size_t)blockIdx.y * GBN * DC;

  floatx4 acc[4][5];
  #pragma unroll
  for (int i = 0; i < 4; ++i)
    #pragma unroll
    for (int j = 0; j < 5; ++j) acc[i][j] = (floatx4){0.f, 0.f, 0.f, 0.f};

  for (int kb = 0; kb < DC / GBK; ++kb) {
    const int k0 = kb * GBK;
    #pragma unroll
    for (int rnd = 0; rnd < 4; ++rnd) {
      int off = rnd * 4096 + tid * 16;
      int m = off >> 7, cl = (off >> 4) & 7, cg = cl ^ (m & 7);
      __builtin_amdgcn_global_load_lds(
          (const __attribute__((address_space(1))) void*)(Ab + (size_t)m * DC + k0 + cg * 8),
          (__attribute__((address_space(3))) void*)((char*)As + off), 16, 0, 0);
    }
    #pragma unroll
    for (int rnd = 0; rnd < 5; ++rnd) {
      int off = rnd * 4096 + tid * 16;
      int n = off >> 7, cl = (off >> 4) & 7, cg = cl ^ (n & 7);
      __builtin_amdgcn_global_load_lds(
          (const __attribute__((address_space(1))) void*)(Bb + (size_t)n * DC + k0 + cg * 8),
          (__attribute__((address_space(3))) void*)((char*)Bs + off), 16, 0, 0);
    }
    __syncthreads();
    #pragma unroll
    for (int ks = 0; ks < 2; ++ks) {
      short8 fa[4], fb[5];
      #pragma unroll
      for (int i = 0; i < 4; ++i) {
        int m = wm + i * 16 + lrow;
        int cl = (ks * 4 + quad) ^ (m & 7);
        fa[i] = *(const short8*)&As[m * GBK + cl * 8];
      }
      #pragma unroll
      for (int j = 0; j < 5; ++j) {
        int n = wn + j * 16 + lrow;
        int cl = (ks * 4 + quad) ^ (n & 7);
        fb[j] = *(const short8*)&Bs[n * GBK + cl * 8];
      }
      #pragma unroll
      for (int i = 0; i < 4; ++i)
        #pragma unroll
        for (int j = 0; j < 5; ++j)
          acc[i][j] = __builtin_amdgcn_mfma_f32_16x16x32_bf16(fa[i], fb[j], acc[i][j], 0, 0, 0);
    }
    __syncthreads();
  }
  // pack epilogue: n<320 -> K[s][c] (SCALE pre-folded via WkvT), else Vt[c][s]
  #pragma unroll
  for (int i = 0; i < 4; ++i)
    #pragma unroll
    for (int j = 0; j < 5; ++j) {
      int n = blockIdx.y * GBN + wn + j * 16 + lrow;
      #pragma unroll
      for (int r = 0; r < 4; ++r) {
        int m = blockIdx.x * GBM + wm + i * 16 + quad * 4 + r;
        if (m < MKV) {
          unsigned um = (unsigned)m;
          int b = (int)(um / 77u), s = (int)(um - (unsigned)b * 77u);
          unsigned short* base = kvp + (size_t)b * (NUM_HEADS * 8192);
          unsigned short v = f2bf(acc[i][j][r]);
          if (n < 320) {
            unsigned un = (unsigned)n;
            int h = (int)(un / 40u), c = (int)(un - (unsigned)h * 40u);
            base[(size_t)h * 8192 + s * 40 + c] = v;
          } else {
            unsigned un = (unsigned)(n - 320);
            int h = (int)(un / 40u), c = (int)(un - (unsigned)h * 40u);
            base[(size_t)h * 8192 + 3200 + c * 104 + s] = v;
          }
        }
      }
    }
}

// --------------------------------------------------------------- fused kernel
// grid = B * T/64 = 1024 blocks, 256 threads (4 waves). LDS 65,280 B ->
// target 2 blocks/CU. Short-indexed layout:
//   qs [64][328] @ 0..20,992  (written at END of phase 1)
//   phase1: As[64][64] @ 0 | Bs[320][64] @ 4,096   (overlays qs region)
//   phase2: Kb[80][40] @ 20,992 (overlaid by Pw 4x[16][104] after QK barrier)
//           Vt[48][104] @ 27,648  (ends 32,640 = 65,280 B exactly)
//   phase3: Bs packed 160x(128B rows) @ 20,992
#define QS_STRIDE 328
#define S0 20992
#define VT0 27648

__global__ __launch_bounds__(256) void fused_attn_kernel(
    const float* __restrict__ x, const unsigned short* __restrict__ WqT,
    const unsigned short* __restrict__ kvp, const unsigned short* __restrict__ WoT,
    const float* __restrict__ bo, float* __restrict__ out) {
  __shared__ __align__(16) unsigned short lds[32640];   // 65,280 B
  unsigned short* qs = lds;
  const int tid = threadIdx.x;
  const int lane = tid & 63, wave = tid >> 6;
  const int lrow = lane & 15, quad = lane >> 4;
  const int b = blockIdx.x >> 6;
  const int t0 = (blockIdx.x & 63) * 64;
  const int wn = wave * 80;

  // ---- Phase 1: qs = bf16(SCALE * x[t0:t0+64] @ Wq), GBK=64, As/Bs over qs
  {
    unsigned short* As = lds;           // [64][64]  8 KB
    unsigned short* Bs = lds + 4096;    // [320][64] 40 KB
    const float* xb = x + ((size_t)b * SEQ_T + t0) * DQ;
    floatx4 acc[4][5];
    #pragma unroll
    for (int i = 0; i < 4; ++i)
      #pragma unroll
      for (int j = 0; j < 5; ++j) acc[i][j] = (floatx4){0.f, 0.f, 0.f, 0.f};

    int xm[2], xcg[2];
    float4 xv[2][2];
    #pragma unroll
    for (int rnd = 0; rnd < 2; ++rnd) {
      int off = rnd * 4096 + tid * 16;
      int m = off >> 7, cl = (off >> 4) & 7;
      xm[rnd] = m; xcg[rnd] = cl ^ (m & 7);
      const float* s = xb + (size_t)m * DQ + xcg[rnd] * 8;
      xv[rnd][0] = *(const float4*)s; xv[rnd][1] = *(const float4*)(s + 4);
    }
    for (int kb = 0; kb < 5; ++kb) {
      #pragma unroll
      for (int rnd = 0; rnd < 2; ++rnd) {   // As <- regs (bf16 convert)
        short8 pk;
        pk[0] = (short)f2bf(xv[rnd][0].x); pk[1] = (short)f2bf(xv[rnd][0].y);
        pk[2] = (short)f2bf(xv[rnd][0].z); pk[3] = (short)f2bf(xv[rnd][0].w);
        pk[4] = (short)f2bf(xv[rnd][1].x); pk[5] = (short)f2bf(xv[rnd][1].y);
        pk[6] = (short)f2bf(xv[rnd][1].z); pk[7] = (short)f2bf(xv[rnd][1].w);
        *(short8*)((char*)As + rnd * 4096 + tid * 16) = pk;
      }
      if (kb < 4) {                         // prefetch next x chunk
        #pragma unroll
        for (int rnd = 0; rnd < 2; ++rnd) {
          const float* s = xb + (size_t)xm[rnd] * DQ + (kb + 1) * 64 + xcg[rnd] * 8;
          xv[rnd][0] = *(const float4*)s; xv[rnd][1] = *(const float4*)(s + 4);
        }
      }
      #pragma unroll
      for (int rnd = 0; rnd < 10; ++rnd) {  // Bs <- WqT (40 KB)
        int off = rnd * 4096 + tid * 16;
        int n = off >> 7, cl = (off >> 4) & 7, cg = cl ^ (n & 7);
        __builtin_amdgcn_global_load_lds(
            (const __attribute__((address_space(1))) void*)(WqT + (size_t)n * 320 + kb * 64 + cg * 8),
            (__attribute__((address_space(3))) void*)((char*)Bs + off), 16, 0, 0);
      }
      __syncthreads();
      #pragma unroll
      for (int ks = 0; ks < 2; ++ks) {
        short8 fa[4], fb[5];
        #pragma unroll
        for (int i = 0; i < 4; ++i) {
          int m = i * 16 + lrow;
          fa[i] = *(const short8*)&As[m * 64 + (((ks * 4 + quad) ^ (m & 7)) * 8)];
        }
        #pragma unroll
        for (int j = 0; j < 5; ++j) {
          int n = wn + j * 16 + lrow;
          fb[j] = *(const short8*)&Bs[n * 64 + (((ks * 4 + quad) ^ (n & 7)) * 8)];
        }
        #pragma unroll
        for (int i = 0; i < 4; ++i)
          #pragma unroll
          for (int j = 0; j < 5; ++j)
            acc[i][j] = __builtin_amdgcn_mfma_f32_16x16x32_bf16(fa[i], fb[j], acc[i][j], 0, 0, 0);
      }
      __syncthreads();
    }
    // qs epilogue (overwrites As/Bs region; last barrier above guards reads)
    #pragma unroll
    for (int i = 0; i < 4; ++i)
      #pragma unroll
      for (int j = 0; j < 5; ++j)
        #pragma unroll
        for (int r = 0; r < 4; ++r)
          qs[(i * 16 + quad * 4 + r) * QS_STRIDE + wn + j * 16 + lrow] =
              f2bf(acc[i][j][r] * SCALE);
  }
  __syncthreads();

  // ---- Phase 2: attention; att overwrites qs band [h*40, h*40+40) ----
  {
    unsigned short* Kb = lds + S0;                    // [80][40] (6,400 B)
    unsigned short* Pw = lds + S0 + wave * 1664;      // [16][104] (overlays Kb)
    unsigned short* Vt = lds + VT0;                   // [48][104] (9,984 B)
    const short8 zero8 = {0, 0, 0, 0, 0, 0, 0, 0};
    for (int h = 0; h < NUM_HEADS; ++h) {
      __syncthreads();   // prev head's Pw/Vt reads done before restage
      const char* kvbh = (const char*)(kvp + (size_t)(b * NUM_HEADS + h) * 8192);
      // K: 6,400 B -> Kb
      __builtin_amdgcn_global_load_lds(
          (const __attribute__((address_space(1))) void*)(kvbh + tid * 16),
          (__attribute__((address_space(3))) void*)((char*)Kb + tid * 16), 16, 0, 0);
      if (tid < 144)
        __builtin_amdgcn_global_load_lds(
            (const __attribute__((address_space(1))) void*)(kvbh + 4096 + tid * 16),
            (__attribute__((address_space(3))) void*)((char*)Kb + 4096 + tid * 16), 16, 0, 0);
      // Vt: 9,984 B -> Vt
      #pragma unroll
      for (int rnd = 0; rnd < 2; ++rnd)
        __builtin_amdgcn_global_load_lds(
            (const __attribute__((address_space(1))) void*)(kvbh + 6400 + rnd * 4096 + tid * 16),
            (__attribute__((address_space(3))) void*)((char*)Vt + rnd * 4096 + tid * 16), 16, 0, 0);
      if (tid < 112)
        __builtin_amdgcn_global_load_lds(
            (const __attribute__((address_space(1))) void*)(kvbh + 6400 + 8192 + tid * 16),
            (__attribute__((address_space(3))) void*)((char*)Vt + 8192 + tid * 16), 16, 0, 0);
      __syncthreads();   // stage ready

      const int qrow = wave * 16 + lrow;
      short8 fq0 = *(const short8*)&qs[qrow * QS_STRIDE + h * DIM_HEAD + quad * 8];
      short8 fq1 = (quad == 0)
                       ? *(const short8*)&qs[qrow * QS_STRIDE + h * DIM_HEAD + 32]
                       : zero8;
      floatx4 sc[5];
      #pragma unroll
      for (int j = 0; j < 5; ++j) sc[j] = (floatx4){0.f, 0.f, 0.f, 0.f};
      #pragma unroll
      for (int j = 0; j < 5; ++j) {
        int srow = j * 16 + lrow;
        short8 fb0 = *(const short8*)&Kb[srow * 40 + quad * 8];
        short8 fb1 = *(const short8*)&Kb[srow * 40 + 32 + quad * 8];  // x0 for quad!=0
        sc[j] = __builtin_amdgcn_mfma_f32_16x16x32_bf16(fq0, fb0, sc[j], 0, 0, 0);
        sc[j] = __builtin_amdgcn_mfma_f32_16x16x32_bf16(fq1, fb1, sc[j], 0, 0, 0);
      }
      __syncthreads();   // all QK reads of Kb done (Pw will overwrite it)

      float lsum[4] = {0.f, 0.f, 0.f, 0.f};
      #pragma unroll
      for (int j = 0; j < 5; ++j) {
        int s = j * 16 + lrow;
        #pragma unroll
        for (int r = 0; r < 4; ++r) {
          float p = (s < SEQ_S) ? __expf(sc[j][r]) : 0.f;
          Pw[(quad * 4 + r) * 104 + s] = f2bf(p);
          lsum[r] += p;
        }
      }
      #pragma unroll
      for (int r = 0; r < 4; ++r) Pw[(quad * 4 + r) * 104 + 80 + lrow] = 0;
      #pragma unroll
      for (int r = 0; r < 4; ++r) {
        float v = lsum[r];
        v += __shfl_xor(v, 1); v += __shfl_xor(v, 2);
        v += __shfl_xor(v, 4); v += __shfl_xor(v, 8);
        lsum[r] = 1.0f / v;
      }
      floatx4 oc[3];
      #pragma unroll
      for (int nj = 0; nj < 3; ++nj) oc[nj] = (floatx4){0.f, 0.f, 0.f, 0.f};
      #pragma unroll
      for (int ks = 0; ks < 3; ++ks) {   // Pw wave-local: lgkmcnt ordering ok
        short8 pa = *(const short8*)&Pw[lrow * 104 + ks * 32 + quad * 8];
        #pragma unroll
        for (int nj = 0; nj < 3; ++nj) {
          short8 vb = *(const short8*)&Vt[(nj * 16 + lrow) * 104 + ks * 32 + quad * 8];
          oc[nj] = __builtin_amdgcn_mfma_f32_16x16x32_bf16(pa, vb, oc[nj], 0, 0, 0);
        }
      }
      #pragma unroll
      for (int nj = 0; nj < 3; ++nj) {   // att -> qs (wave-local rows)
        int c = nj * 16 + lrow;
        if (c < DIM_HEAD) {
          #pragma unroll
          for (int r = 0; r < 4; ++r)
            qs[(wave * 16 + quad * 4 + r) * QS_STRIDE + h * DIM_HEAD + c] =
                f2bf(oc[nj][r] * lsum[r]);
        }
      }
    }
  }
  __syncthreads();

  // ---- Phase 3: out = att @ Wo + bo; Bs pair-packed 128B rows + XOR8 ----
  {
    unsigned short* Bs = lds + S0;   // 20,480 B: unit(r128, slot)
    floatx4 acc[4][5];
    #pragma unroll
    for (int i = 0; i < 4; ++i)
      #pragma unroll
      for (int j = 0; j < 5; ++j) acc[i][j] = (floatx4){0.f, 0.f, 0.f, 0.f};
    for (int kb = 0; kb < 10; ++kb) {
      __syncthreads();   // prev kb's Bs reads done (kb=0: phase-2 regions)
      #pragma unroll
      for (int rnd = 0; rnd < 5; ++rnd) {
        int off = rnd * 4096 + tid * 16;
        int U = off >> 4, r128 = U >> 3, sl = U & 7;
        int sp = sl ^ (r128 & 7);
        int n = r128 * 2 + (sp >> 2), kg = sp & 3;
        __builtin_amdgcn_global_load_lds(
            (const __attribute__((address_space(1))) void*)(WoT + (size_t)n * 320 + kb * 32 + kg * 8),
            (__attribute__((address_space(3))) void*)((char*)Bs + off), 16, 0, 0);
      }
      __syncthreads();
      short8 fa[4], fb[5];
      #pragma unroll
      for (int i = 0; i < 4; ++i)
        fa[i] = *(const short8*)&qs[(i * 16 + lrow) * QS_STRIDE + kb * 32 + quad * 8];
      #pragma unroll
      for (int j = 0; j < 5; ++j) {
        int n = wn + j * 16 + lrow;
        int r128 = n >> 1;
        int sl = (((n & 1) << 2) | quad) ^ (r128 & 7);
        fb[j] = *(const short8*)((const char*)Bs + r128 * 128 + sl * 16);
      }
      #pragma unroll
      for (int i = 0; i < 4; ++i)
        #pragma unroll
        for (int j = 0; j < 5; ++j)
          acc[i][j] = __builtin_amdgcn_mfma_f32_16x16x32_bf16(fa[i], fb[j], acc[i][j], 0, 0, 0);
    }
    float* ob = out + ((size_t)b * SEQ_T + t0) * DQ;
    #pragma unroll
    for (int i = 0; i < 4; ++i)
      #pragma unroll
      for (int j = 0; j < 5; ++j) {
        int n = wn + j * 16 + lrow;
        float bv = bo[n];
        #pragma unroll
        for (int r = 0; r < 4; ++r)
          ob[(size_t)(i * 16 + quad * 4 + r) * DQ + n] = acc[i][j][r] + bv;
      }
  }
}

// -------------------------------------------------------------------- launch
extern "C" void kernel_launch(void* const* d_in, const int* in_sizes, int n_in,
                              void* d_out, int out_size, void* d_ws, size_t ws_size,
                              hipStream_t stream) {
  const float* x   = (const float*)d_in[0];
  const float* ctx = (const float*)d_in[1];
  const float* Wq  = (const float*)d_in[2];
  const float* Wk  = (const float*)d_in[3];
  const float* Wv  = (const float*)d_in[4];
  const float* Wo  = (const float*)d_in[5];
  const float* bo  = (const float*)d_in[6];
  float* out = (float*)d_out;

  char* w = (char*)d_ws;
  unsigned short* ctxb = (unsigned short*)(w);             //  1,966,080 B
  unsigned short* WkvT = (unsigned short*)(w + 1966080);   //    983,040 B
  unsigned short* WqT  = (unsigned short*)(w + 2949120);   //    204,800 B
  unsigned short* WoT  = (unsigned short*)(w + 3153920);   //    204,800 B
  unsigned short* kvp  = (unsigned short*)(w + 3358720);   //  2,097,152 B -> 5,455,872

  hipMemsetAsync(kvp, 0, 2097152, stream);   // zero-fill kvp padding
  hipLaunchKernelGGL(convert_ctx_kernel, dim3(CTXBLKS), dim3(256), 0, stream, ctx, ctxb);
  hipLaunchKernelGGL(transpose_w_kernel, dim3(24, 10, 4), dim3(256), 0, stream,
                     Wq, Wo, Wk, Wv, WqT, WoT, WkvT);
  hipLaunchKernelGGL(gemm_kv_pack_kernel, dim3(MKV_PAD / GBM, 640 / GBN),
                     dim3(256), 0, stream, ctxb, WkvT, kvp);
  hipLaunchKernelGGL(fused_attn_kernel, dim3(BATCH * (SEQ_T / 64)), dim3(256), 0, stream,
                     x, WqT, kvp, WoT, bo, out);
}

// Round 4
// 291.746 us; speedup vs baseline: 1.0781x; 1.0222x over previous
//
#include <hip/hip_runtime.h>
#include <math.h>

// Round 9: barrier-free fused kernel, LDS = 40,960 B (qs only) -> guaranteed
// 2 blocks/CU (pool >= 96,256 proven). B-operands (Wq/Wo/K/V) are per-wave
// 16B direct-global loads from L2 (no LDS staging, no barriers). Swapped QK^T
// puts P column-major per lane; softmax + P-redistribution fully in-register
// (shfl) -> phase 2 has zero barriers. 5 __syncthreads total (was ~54).
// kv GEMM rewritten barrier-free too; convert_ctx kernel deleted.

#define NUM_HEADS 8
#define DIM_HEAD 40
#define INNER 320
#define DQ 320
#define DC 768
#define SEQ_T 4096
#define SEQ_S 77
#define BATCH 16
#define MKV 1232                  // BATCH*SEQ_S
#define MKV_PAD 1280
#define SCALE 0.39763536438352531f

typedef __attribute__((ext_vector_type(8))) short short8;
typedef __attribute__((ext_vector_type(4))) float floatx4;

__device__ __forceinline__ unsigned short f2bf(float f) {
  unsigned u = __float_as_uint(f);
  u += 0x7FFFu + ((u >> 16) & 1u);   // RNE
  return (unsigned short)(u >> 16);
}

// qs swizzle: 16B-unit index for (row, unit-col). 40 units per 320-short row.
__device__ __forceinline__ int qsi(int row, int uc) {
  return (row * 40 + (uc ^ (row & 7))) * 8;
}

// -------------------------------------- transpose weights (fp32 -> bf16^T)
// Wq and Wk pre-scaled by SCALE (dim_head^-1/4 each; net 1/sqrt(dim_head)).
__global__ __launch_bounds__(256) void transpose_w_kernel(
    const float* __restrict__ Wq, const float* __restrict__ Wo,
    const float* __restrict__ Wk, const float* __restrict__ Wv,
    unsigned short* __restrict__ WqT, unsigned short* __restrict__ WoT,
    unsigned short* __restrict__ WkvT) {
  const int z = blockIdx.z;
  const float* W; unsigned short* WT; int KD; float scl = 1.0f;
  if (z == 0)      { W = Wq; WT = WqT;  KD = 320; scl = SCALE; }
  else if (z == 1) { W = Wo; WT = WoT;  KD = 320; }
  else if (z == 2) { W = Wk; WT = WkvT; KD = DC; scl = SCALE; }
  else             { W = Wv; WT = WkvT + (size_t)INNER * DC; KD = DC; }
  const int k0 = blockIdx.x * 32;
  if (k0 >= KD) return;
  const int n0 = blockIdx.y * 32;
  __shared__ float tile[32][33];
  int tx = threadIdx.x & 31, ty = threadIdx.x >> 5;
  #pragma unroll
  for (int r = 0; r < 4; ++r)
    tile[ty + r * 8][tx] = W[(size_t)(k0 + ty + r * 8) * 320 + n0 + tx];
  __syncthreads();
  #pragma unroll
  for (int r = 0; r < 4; ++r)
    WT[(size_t)(n0 + ty + r * 8) * KD + k0 + tx] = f2bf(tile[tx][ty + r * 8] * scl);
}

// ---------------- kv GEMM (barrier-free) with fused pack epilogue ----------
// grid (40, 2), 256 thr. A = ctx fp32 (padded rows -> 0) staged ONCE to LDS
// as bf16 [32][768] swizzled; B fragments direct-global from WkvT (L2).
// Packs to kvp[(b*8+h)]: K[80][40] | Vt[48][104] (padding pre-zeroed).
__global__ __launch_bounds__(256) void gemm_kv_pack_kernel(
    const float* __restrict__ ctx, const unsigned short* __restrict__ WkvT,
    unsigned short* __restrict__ kvp) {
  __shared__ __align__(16) unsigned short As[32 * 768];   // 49,152 B
  const int tid = threadIdx.x;
  const int lane = tid & 63, wave = tid >> 6;
  const int lrow = lane & 15, quad = lane >> 4;
  const int m0 = blockIdx.x * 32;
  const int wn = blockIdx.y * 320 + wave * 80;

  {  // stage ctx[m0:m0+32][0:768] -> bf16 LDS (swizzled), pad rows zero
    int row = tid >> 3, ub = tid & 7;
    const float* src0 = ctx + (size_t)(m0 + row) * DC;
    bool valid = (m0 + row) < MKV;
    #pragma unroll
    for (int it = 0; it < 12; ++it) {
      int uc = ub + it * 8;
      float4 a = {0.f, 0.f, 0.f, 0.f}, c2 = {0.f, 0.f, 0.f, 0.f};
      if (valid) {
        a  = *(const float4*)(src0 + uc * 8);
        c2 = *(const float4*)(src0 + uc * 8 + 4);
      }
      short8 pk;
      pk[0] = (short)f2bf(a.x);  pk[1] = (short)f2bf(a.y);
      pk[2] = (short)f2bf(a.z);  pk[3] = (short)f2bf(a.w);
      pk[4] = (short)f2bf(c2.x); pk[5] = (short)f2bf(c2.y);
      pk[6] = (short)f2bf(c2.z); pk[7] = (short)f2bf(c2.w);
      *(short8*)&As[(row * 96 + (uc ^ (row & 7))) * 8] = pk;
    }
  }
  __syncthreads();

  floatx4 acc[2][5];
  #pragma unroll
  for (int i = 0; i < 2; ++i)
    #pragma unroll
    for (int j = 0; j < 5; ++j) acc[i][j] = (floatx4){0.f, 0.f, 0.f, 0.f};

  auto kvload = [&](int kb, short8 (&fb)[5], short8 (&fa)[2]) {
    #pragma unroll
    for (int j = 0; j < 5; ++j)
      fb[j] = *(const short8*)(WkvT + (size_t)(wn + j * 16 + lrow) * DC + kb * 32 + quad * 8);
    #pragma unroll
    for (int i = 0; i < 2; ++i) {
      int m = i * 16 + lrow;
      fa[i] = *(const short8*)&As[(m * 96 + ((kb * 4 + quad) ^ (m & 7))) * 8];
    }
  };
  auto mm25 = [&](short8 (&fa)[2], short8 (&fb)[5]) {
    #pragma unroll
    for (int i = 0; i < 2; ++i)
      #pragma unroll
      for (int j = 0; j < 5; ++j)
        acc[i][j] = __builtin_amdgcn_mfma_f32_16x16x32_bf16(fa[i], fb[j], acc[i][j], 0, 0, 0);
  };

  short8 fbA[5], fbB[5], faA[2], faB[2];
  kvload(0, fbA, faA);
  #pragma unroll
  for (int t = 0; t < 12; ++t) {
    kvload(2 * t + 1, fbB, faB);
    mm25(faA, fbA);
    if (2 * t + 2 < 24) kvload(2 * t + 2, fbA, faA);
    mm25(faB, fbB);
  }

  // pack epilogue: n<320 -> K[s][c] (SCALE pre-folded), else Vt[c][s]
  #pragma unroll
  for (int i = 0; i < 2; ++i)
    #pragma unroll
    for (int j = 0; j < 5; ++j) {
      int n = wn + j * 16 + lrow;
      #pragma unroll
      for (int r = 0; r < 4; ++r) {
        int m = m0 + i * 16 + quad * 4 + r;
        if (m < MKV) {
          unsigned um = (unsigned)m;
          int b = (int)(um / 77u), s = (int)(um - (unsigned)b * 77u);
          unsigned short* base = kvp + (size_t)b * (NUM_HEADS * 8192);
          unsigned short v = f2bf(acc[i][j][r]);
          if (n < 320) {
            unsigned un = (unsigned)n;
            int h = (int)(un / 40u), c = (int)(un - (unsigned)h * 40u);
            base[(size_t)h * 8192 + s * 40 + c] = v;
          } else {
            unsigned un = (unsigned)(n - 320);
            int h = (int)(un / 40u), c = (int)(un - (unsigned)h * 40u);
            base[(size_t)h * 8192 + 3200 + c * 104 + s] = v;
          }
        }
      }
    }
}

// --------------------------------------------------------------- fused kernel
// grid = B * T/64 = 1024 blocks, 256 threads (4 waves). LDS 40,960 B (qs only)
// -> 2 blocks/CU guaranteed. 5 barriers total; phases internally barrier-free.
__global__ __launch_bounds__(256) void fused_attn_kernel(
    const float* __restrict__ x, const unsigned short* __restrict__ WqT,
    const unsigned short* __restrict__ kvp, const unsigned short* __restrict__ WoT,
    const float* __restrict__ bo, float* __restrict__ out) {
  __shared__ __align__(16) unsigned short qs[64 * 320];   // 40,960 B
  const int tid = threadIdx.x;
  const int lane = tid & 63, wave = tid >> 6;
  const int lrow = lane & 15, quad = lane >> 4;
  const int b = blockIdx.x >> 6;
  const int t0 = (blockIdx.x & 63) * 64;
  const int wn = wave * 80;

  // ---- Phase 0: stage x tile -> bf16 qs (swizzled); overwritten by q later
  {
    const float* xb = x + ((size_t)b * SEQ_T + t0) * DQ;
    int row = tid >> 2, ub = tid & 3;
    const float* src0 = xb + (size_t)row * DQ;
    #pragma unroll
    for (int it = 0; it < 10; ++it) {
      int uc = ub + it * 4;
      float4 a  = *(const float4*)(src0 + uc * 8);
      float4 c2 = *(const float4*)(src0 + uc * 8 + 4);
      short8 pk;
      pk[0] = (short)f2bf(a.x);  pk[1] = (short)f2bf(a.y);
      pk[2] = (short)f2bf(a.z);  pk[3] = (short)f2bf(a.w);
      pk[4] = (short)f2bf(c2.x); pk[5] = (short)f2bf(c2.y);
      pk[6] = (short)f2bf(c2.z); pk[7] = (short)f2bf(c2.w);
      *(short8*)&qs[qsi(row, uc)] = pk;
    }
  }
  __syncthreads();

  // ---- Phase 1: q = x @ WqT (SCALE folded into WqT), barrier-free kb loop
  {
    floatx4 acc[4][5];
    #pragma unroll
    for (int i = 0; i < 4; ++i)
      #pragma unroll
      for (int j = 0; j < 5; ++j) acc[i][j] = (floatx4){0.f, 0.f, 0.f, 0.f};

    auto ld = [&](int kb, short8 (&fb)[5], short8 (&fa)[4]) {
      #pragma unroll
      for (int j = 0; j < 5; ++j)
        fb[j] = *(const short8*)(WqT + (size_t)(wn + j * 16 + lrow) * 320 + kb * 32 + quad * 8);
      #pragma unroll
      for (int i = 0; i < 4; ++i) {
        int m = i * 16 + lrow;
        fa[i] = *(const short8*)&qs[qsi(m, kb * 4 + quad)];
      }
    };
    auto mm = [&](short8 (&fa)[4], short8 (&fb)[5]) {
      #pragma unroll
      for (int i = 0; i < 4; ++i)
        #pragma unroll
        for (int j = 0; j < 5; ++j)
          acc[i][j] = __builtin_amdgcn_mfma_f32_16x16x32_bf16(fa[i], fb[j], acc[i][j], 0, 0, 0);
    };

    short8 fbA[5], fbB[5], faA[4], faB[4];
    ld(0, fbA, faA);
    #pragma unroll
    for (int t = 0; t < 5; ++t) {
      ld(2 * t + 1, fbB, faB);
      mm(faA, fbA);
      if (2 * t + 2 < 10) ld(2 * t + 2, fbA, faA);
      mm(faB, fbB);
    }
    __syncthreads();   // all waves done reading x from qs
    #pragma unroll
    for (int i = 0; i < 4; ++i)
      #pragma unroll
      for (int j = 0; j < 5; ++j)
        #pragma unroll
        for (int r = 0; r < 4; ++r) {
          int row = i * 16 + quad * 4 + r, c = wn + j * 16 + lrow;
          qs[(row * 40 + ((c >> 3) ^ (row & 7))) * 8 + (c & 7)] = f2bf(acc[i][j][r]);
        }
  }
  __syncthreads();   // q visible to all waves

  // ---- Phase 2: attention (swapped QK^T, in-register softmax+redistribute).
  // Wave owns q rows [16w,16w+16); zero barriers. att overwrites qs in place.
  {
    const int W = wave * 16;
    const int qrow = W + lrow;
    const short8 zero8 = {0, 0, 0, 0, 0, 0, 0, 0};
    const int sl_a0 = (quad & 1) * 32 + lrow;   // P redistribution src lanes
    const int sl_a1 = sl_a0 + 16;
    const bool jhi = quad >= 2;

    #pragma unroll 1
    for (int h = 0; h < NUM_HEADS; ++h) {
      const unsigned short* kvt = kvp + (size_t)(b * NUM_HEADS + h) * 8192;
      // V fragments (issued early; consumed after softmax)
      short8 vb0[3], vb1[3], vb2[3];
      #pragma unroll
      for (int nj = 0; nj < 3; ++nj) {
        const unsigned short* vtb = kvt + 3200 + (size_t)(nj * 16 + lrow) * 104 + quad * 8;
        vb0[nj] = *(const short8*)(vtb);
        vb1[nj] = *(const short8*)(vtb + 32);
        vb2[nj] = *(const short8*)(vtb + 64);
      }
      // K fragments (A operand of swapped QK^T)
      short8 ka0[5], ka1[5];
      #pragma unroll
      for (int j = 0; j < 5; ++j) {
        const unsigned short* kbp = kvt + (size_t)(j * 16 + lrow) * 40;
        ka0[j] = *(const short8*)(kbp + quad * 8);
        ka1[j] = *(const short8*)(kbp + 32 + quad * 8);   // quads 1-3: garbage x 0
      }
      short8 fq0 = *(const short8*)&qs[qsi(qrow, h * 5 + quad)];
      short8 fq1 = (quad == 0) ? *(const short8*)&qs[qsi(qrow, h * 5 + 4)] : zero8;

      floatx4 sc[5];
      #pragma unroll
      for (int j = 0; j < 5; ++j) sc[j] = (floatx4){0.f, 0.f, 0.f, 0.f};
      #pragma unroll
      for (int j = 0; j < 5; ++j) {
        sc[j] = __builtin_amdgcn_mfma_f32_16x16x32_bf16(ka0[j], fq0, sc[j], 0, 0, 0);
        sc[j] = __builtin_amdgcn_mfma_f32_16x16x32_bf16(ka1[j], fq1, sc[j], 0, 0, 0);
      }
      // sc[j][r] = P^T[s = j*16 + quad*4 + r][qrow = W + lrow]
      float p[5][4]; float csum = 0.f;
      #pragma unroll
      for (int j = 0; j < 5; ++j)
        #pragma unroll
        for (int r = 0; r < 4; ++r) {
          int s = j * 16 + quad * 4 + r;
          float v = (s < SEQ_S) ? __expf(sc[j][r]) : 0.f;
          p[j][r] = v; csum += v;
        }
      csum += __shfl_xor(csum, 16);
      csum += __shfl_xor(csum, 32);
      float inv = 1.0f / csum;        // per q-row (col l of sc')

      unsigned pk0[5], pk1[5];
      #pragma unroll
      for (int j = 0; j < 5; ++j) {
        pk0[j] = (unsigned)f2bf(p[j][0]) | ((unsigned)f2bf(p[j][1]) << 16);
        pk1[j] = (unsigned)f2bf(p[j][2]) | ((unsigned)f2bf(p[j][3]) << 16);
      }
      // redistribute P^T -> PV A-fragments (pa[ks] elem e = P[row=l][s=ks*32+q*8+e])
      floatx4 oc[3];
      #pragma unroll
      for (int nj = 0; nj < 3; ++nj) oc[nj] = (floatx4){0.f, 0.f, 0.f, 0.f};
      #pragma unroll
      for (int ks = 0; ks < 3; ++ks) {
        unsigned wA0 = __shfl(pk0[2 * ks], sl_a0);
        unsigned wA1 = __shfl(pk1[2 * ks], sl_a0);
        unsigned wA2 = __shfl(pk0[2 * ks], sl_a1);
        unsigned wA3 = __shfl(pk1[2 * ks], sl_a1);
        unsigned wB0 = (2 * ks + 1 < 5) ? __shfl(pk0[2 * ks + 1], sl_a0) : 0u;
        unsigned wB1 = (2 * ks + 1 < 5) ? __shfl(pk1[2 * ks + 1], sl_a0) : 0u;
        unsigned wB2 = (2 * ks + 1 < 5) ? __shfl(pk0[2 * ks + 1], sl_a1) : 0u;
        unsigned wB3 = (2 * ks + 1 < 5) ? __shfl(pk1[2 * ks + 1], sl_a1) : 0u;
        union { unsigned u[4]; short8 s8; } pu;
        pu.u[0] = jhi ? wB0 : wA0;
        pu.u[1] = jhi ? wB1 : wA1;
        pu.u[2] = jhi ? wB2 : wA2;
        pu.u[3] = jhi ? wB3 : wA3;
        short8* vb = (ks == 0) ? vb0 : (ks == 1) ? vb1 : vb2;
        #pragma unroll
        for (int nj = 0; nj < 3; ++nj)
          oc[nj] = __builtin_amdgcn_mfma_f32_16x16x32_bf16(pu.s8, vb[nj], oc[nj], 0, 0, 0);
      }
      // normalize (per output row) and write att into qs band [h*40, h*40+40)
      float invr[4];
      #pragma unroll
      for (int r = 0; r < 4; ++r) invr[r] = __shfl(inv, quad * 4 + r);
      #pragma unroll
      for (int nj = 0; nj < 3; ++nj) {
        int c = nj * 16 + lrow;
        if (c < DIM_HEAD) {
          #pragma unroll
          for (int r = 0; r < 4; ++r) {
            int row = W + quad * 4 + r, cc = h * 40 + c;
            qs[(row * 40 + ((cc >> 3) ^ (row & 7))) * 8 + (cc & 7)] =
                f2bf(oc[nj][r] * invr[r]);
          }
        }
      }
    }
  }
  __syncthreads();   // att ready for all waves

  // ---- Phase 3: out = att @ WoT + bo, barrier-free kb loop
  {
    floatx4 acc[4][5];
    #pragma unroll
    for (int i = 0; i < 4; ++i)
      #pragma unroll
      for (int j = 0; j < 5; ++j) acc[i][j] = (floatx4){0.f, 0.f, 0.f, 0.f};

    auto ld = [&](int kb, short8 (&fb)[5], short8 (&fa)[4]) {
      #pragma unroll
      for (int j = 0; j < 5; ++j)
        fb[j] = *(const short8*)(WoT + (size_t)(wn + j * 16 + lrow) * 320 + kb * 32 + quad * 8);
      #pragma unroll
      for (int i = 0; i < 4; ++i) {
        int m = i * 16 + lrow;
        fa[i] = *(const short8*)&qs[qsi(m, kb * 4 + quad)];
      }
    };
    auto mm = [&](short8 (&fa)[4], short8 (&fb)[5]) {
      #pragma unroll
      for (int i = 0; i < 4; ++i)
        #pragma unroll
        for (int j = 0; j < 5; ++j)
          acc[i][j] = __builtin_amdgcn_mfma_f32_16x16x32_bf16(fa[i], fb[j], acc[i][j], 0, 0, 0);
    };

    short8 fbA[5], fbB[5], faA[4], faB[4];
    ld(0, fbA, faA);
    #pragma unroll
    for (int t = 0; t < 5; ++t) {
      ld(2 * t + 1, fbB, faB);
      mm(faA, fbA);
      if (2 * t + 2 < 10) ld(2 * t + 2, fbA, faA);
      mm(faB, fbB);
    }
    float* ob = out + ((size_t)b * SEQ_T + t0) * DQ;
    #pragma unroll
    for (int i = 0; i < 4; ++i)
      #pragma unroll
      for (int j = 0; j < 5; ++j) {
        int n = wn + j * 16 + lrow;
        float bv = bo[n];
        #pragma unroll
        for (int r = 0; r < 4; ++r)
          ob[(size_t)(i * 16 + quad * 4 + r) * DQ + n] = acc[i][j][r] + bv;
      }
  }
}

// -------------------------------------------------------------------- launch
extern "C" void kernel_launch(void* const* d_in, const int* in_sizes, int n_in,
                              void* d_out, int out_size, void* d_ws, size_t ws_size,
                              hipStream_t stream) {
  const float* x   = (const float*)d_in[0];
  const float* ctx = (const float*)d_in[1];
  const float* Wq  = (const float*)d_in[2];
  const float* Wk  = (const float*)d_in[3];
  const float* Wv  = (const float*)d_in[4];
  const float* Wo  = (const float*)d_in[5];
  const float* bo  = (const float*)d_in[6];
  float* out = (float*)d_out;

  char* w = (char*)d_ws;
  unsigned short* WkvT = (unsigned short*)(w);             //   983,040 B
  unsigned short* WqT  = (unsigned short*)(w + 983040);    //   204,800 B
  unsigned short* WoT  = (unsigned short*)(w + 1187840);   //   204,800 B
  unsigned short* kvp  = (unsigned short*)(w + 1392640);   // 2,097,152 B -> 3,489,792

  hipMemsetAsync(kvp, 0, 2097152, stream);   // zero-fill kvp padding
  hipLaunchKernelGGL(transpose_w_kernel, dim3(24, 10, 4), dim3(256), 0, stream,
                     Wq, Wo, Wk, Wv, WqT, WoT, WkvT);
  hipLaunchKernelGGL(gemm_kv_pack_kernel, dim3(MKV_PAD / 32, 2), dim3(256), 0, stream,
                     ctx, WkvT, kvp);
  hipLaunchKernelGGL(fused_attn_kernel, dim3(BATCH * (SEQ_T / 64)), dim3(256), 0, stream,
                     x, WqT, kvp, WoT, bo, out);
}